// Round 3
// baseline (2290.362 us; speedup 1.0000x reference)
//
#include <hip/hip_runtime.h>

#define B 128
#define T 1500
#define NI 80        // N_MELS
#define H 128        // HIDDEN
#define G 384        // 3*H

__device__ __forceinline__ float sigf(float x) { return 1.0f / (1.0f + __expf(-x)); }
__device__ __forceinline__ float tanhfast(float x) { return 1.0f - 2.0f / (1.0f + __expf(2.0f * x)); }
__device__ __forceinline__ float dot4(float acc, float4 a, float4 b) {
    return fmaf(a.x, b.x, fmaf(a.y, b.y, fmaf(a.z, b.z, fmaf(a.w, b.w, acc))));
}

// ---------------- gx GEMM: gx[b][tl][g] = b_ih[g] + x[b,t0+tl,:]·w_ih[g,:] ----------------
// Thread owns 2 adjacent timesteps (x rows in VGPRs). w row address is wave-uniform
// -> L1 broadcast / scalar-load candidate. No LDS, no barriers.
__global__ __launch_bounds__(256)
void gx_gemm_kernel(const float* __restrict__ x, const float* __restrict__ w_ih,
                    const float* __restrict__ b_ih, float* __restrict__ gx,
                    int t0, int ct) {
    int b = blockIdx.x % B;
    int tile = blockIdx.x / B;
    int tl = tile * 512 + 2 * (int)threadIdx.x;
    if (tl >= ct) return;
    bool v1 = tl + 1 < ct;

    float4 xa[20], xb[20];
    const float4* xr0 = (const float4*)(x + ((size_t)b * T + (size_t)(t0 + tl)) * NI);
#pragma unroll
    for (int c = 0; c < 20; ++c) xa[c] = xr0[c];
#pragma unroll
    for (int c = 0; c < 20; ++c) xb[c] = make_float4(0.f, 0.f, 0.f, 0.f);
    if (v1) {
        const float4* xr1 = (const float4*)(x + ((size_t)b * T + (size_t)(t0 + tl + 1)) * NI);
#pragma unroll
        for (int c = 0; c < 20; ++c) xb[c] = xr1[c];
    }

    float* gout = gx + ((size_t)b * ct + (size_t)tl) * G;
    for (int g = 0; g < G; ++g) {
        const float4* wr = (const float4*)(w_ih + (size_t)g * NI);
        float a0 = 0.f, a1 = 0.f, a2 = 0.f, a3 = 0.f;
        float c0 = 0.f, c1 = 0.f, c2 = 0.f, c3 = 0.f;
#pragma unroll
        for (int c = 0; c < 20; ++c) {
            float4 wv = wr[c];
            a0 = fmaf(wv.x, xa[c].x, a0); a1 = fmaf(wv.y, xa[c].y, a1);
            a2 = fmaf(wv.z, xa[c].z, a2); a3 = fmaf(wv.w, xa[c].w, a3);
            c0 = fmaf(wv.x, xb[c].x, c0); c1 = fmaf(wv.y, xb[c].y, c1);
            c2 = fmaf(wv.z, xb[c].z, c2); c3 = fmaf(wv.w, xb[c].w, c3);
        }
        float bias = b_ih[g];
        gout[g] = bias + ((a0 + a1) + (a2 + a3));
        if (v1) gout[G + g] = bias + ((c0 + c1) + (c2 + c3));
    }
}

// ---------------- scan ----------------
// 512 threads: tid = jp*8 + q, jp in [0,64), q in [0,8).
// Thread computes partial dots for BOTH j=jp and j=jp+64 over k in [16q,16q+16)
// (one h slice feeds 6 accumulators -> half the LDS broadcast reads).
// Reduce: xor1,xor2 (DPP) then one xor4 exchange of the 3 foreign partials.
// Quads q<4 own j=jp; quads q>=4 own j=jp+64.
// Raw s_barrier with lgkmcnt-only wait => gx prefetch loads stay in flight (no vmcnt drain).
__global__ __launch_bounds__(512)
void scan_kernel(const float* __restrict__ gx, const float* __restrict__ w_hh,
                 const float* __restrict__ b_hh, float* __restrict__ h_state,
                 int ct, int first, int last,
                 const float* __restrict__ x,
                 const float* __restrict__ w_ih_b, const float* __restrict__ b_ih_b,
                 const float* __restrict__ b_hh_b,
                 const float* __restrict__ w1, const float* __restrict__ b1,
                 const float* __restrict__ w2, const float* __restrict__ b2,
                 float* __restrict__ out) {
    int b = blockIdx.x;
    int tid = threadIdx.x;
    int jp = tid >> 3;
    int q = tid & 7;
    bool hiq = (q & 4) != 0;
    int j1 = jp + (hiq ? 64 : 0);          // the j this lane produces gates for
    int jpad1 = j1 + ((j1 >> 4) << 2);     // padded LDS index (4 pad words per 16)

    __shared__ __align__(16) float hs0[160];
    __shared__ __align__(16) float hs1[160];
    __shared__ __align__(16) float tail_gx[G];
    __shared__ __align__(16) float last_s[2 * H];
    __shared__ __align__(16) float xb_s[NI];

    // W_hh fragments: rows {jp, jp+H, jp+2H, jp+64, jp+64+H, jp+64+2H}, k-slice [16q,16q+16)
    float4 W[24];
    {
        const float4* wp = (const float4*)w_hh;
        size_t base = (size_t)jp * 32 + 4 * q;   // row j -> j*32 float4s
#pragma unroll
        for (int i = 0; i < 4; ++i) {
            W[0  + i] = wp[base + i];
            W[4  + i] = wp[base + (size_t)H * 32 + i];
            W[8  + i] = wp[base + (size_t)2 * H * 32 + i];
            W[12 + i] = wp[base + (size_t)64 * 32 + i];
            W[16 + i] = wp[base + (size_t)(64 + H) * 32 + i];
            W[20 + i] = wp[base + (size_t)(64 + 2 * H) * 32 + i];
        }
    }
    float br1 = b_hh[j1], bz1 = b_hh[j1 + H], bn1 = b_hh[j1 + 2 * H];

    float h_cur = 0.f;
    if (!first) h_cur = h_state[b * H + j1];
    if ((q & 3) == 0) hs0[jpad1] = h_cur;

    // gx prefetch registers, distance 2 (set A for even t, set B for odd t)
    float ga0, ga1, ga2, gb0 = 0.f, gb1 = 0.f, gb2 = 0.f;
    {
        const float* gp = gx + (size_t)b * ct * G;
        ga0 = gp[j1]; ga1 = gp[j1 + H]; ga2 = gp[j1 + 2 * H];
        if (ct > 1) { gb0 = gp[G + j1]; gb1 = gp[G + j1 + H]; gb2 = gp[G + j1 + 2 * H]; }
    }
    asm volatile("s_waitcnt lgkmcnt(0)\n\ts_barrier" ::: "memory");

    auto step = [&](int TL, const float* SRC, float* DST, float& g0, float& g1, float& g2) {
        const float4* hv4 = ((const float4*)SRC) + 5 * q;
        float4 h0 = hv4[0], h1 = hv4[1], h2 = hv4[2], h3 = hv4[3];
        float ar0 = 0.f, az0 = 0.f, an0 = 0.f, ar1 = 0.f, az1 = 0.f, an1 = 0.f;
        ar0 = dot4(ar0, W[0],  h0); az0 = dot4(az0, W[4],  h0); an0 = dot4(an0, W[8],  h0);
        ar1 = dot4(ar1, W[12], h0); az1 = dot4(az1, W[16], h0); an1 = dot4(an1, W[20], h0);
        ar0 = dot4(ar0, W[1],  h1); az0 = dot4(az0, W[5],  h1); an0 = dot4(an0, W[9],  h1);
        ar1 = dot4(ar1, W[13], h1); az1 = dot4(az1, W[17], h1); an1 = dot4(an1, W[21], h1);
        ar0 = dot4(ar0, W[2],  h2); az0 = dot4(az0, W[6],  h2); an0 = dot4(an0, W[10], h2);
        ar1 = dot4(ar1, W[14], h2); az1 = dot4(az1, W[18], h2); an1 = dot4(an1, W[22], h2);
        ar0 = dot4(ar0, W[3],  h3); az0 = dot4(az0, W[7],  h3); an0 = dot4(an0, W[11], h3);
        ar1 = dot4(ar1, W[15], h3); az1 = dot4(az1, W[19], h3); an1 = dot4(an1, W[23], h3);
        ar0 += __shfl_xor(ar0, 1); az0 += __shfl_xor(az0, 1); an0 += __shfl_xor(an0, 1);
        ar1 += __shfl_xor(ar1, 1); az1 += __shfl_xor(az1, 1); an1 += __shfl_xor(an1, 1);
        ar0 += __shfl_xor(ar0, 2); az0 += __shfl_xor(az0, 2); an0 += __shfl_xor(an0, 2);
        ar1 += __shfl_xor(ar1, 2); az1 += __shfl_xor(az1, 2); an1 += __shfl_xor(an1, 2);
        float fr = hiq ? ar0 : ar1, fz = hiq ? az0 : az1, fn = hiq ? an0 : an1;
        fr = __shfl_xor(fr, 4); fz = __shfl_xor(fz, 4); fn = __shfl_xor(fn, 4);
        float sr = (hiq ? ar1 : ar0) + fr;
        float sz = (hiq ? az1 : az0) + fz;
        float sn = (hiq ? an1 : an0) + fn;
        float r = sigf(g0 + br1 + sr);
        float z = sigf(g1 + bz1 + sz);
        float n = tanhfast(g2 + r * (bn1 + sn));
        h_cur = (1.f - z) * n + z * h_cur;
        if ((q & 3) == 0) DST[jpad1] = h_cur;
        if (TL + 2 < ct) {
            const float* gp = gx + ((size_t)b * ct + TL + 2) * G;
            g0 = gp[j1]; g1 = gp[j1 + H]; g2 = gp[j1 + 2 * H];
        }
        asm volatile("s_waitcnt lgkmcnt(0)\n\ts_barrier" ::: "memory");
    };

    int tl = 0;
    for (; tl + 1 < ct; tl += 2) {
        step(tl,     hs0, hs1, ga0, ga1, ga2);
        step(tl + 1, hs1, hs0, gb0, gb1, gb2);
    }
    if (tl < ct) step(tl, hs0, hs1, ga0, ga1, ga2);

    if (!last) {
        if ((q & 3) == 0) h_state[b * H + j1] = h_cur;
        return;
    }

    // ---- backward single step (h0 = 0) + MLP head ----
    if (tid < NI) xb_s[tid] = x[((size_t)b * T + (T - 1)) * NI + tid];
    if ((q & 3) == 0) last_s[j1] = h_cur;  // forward final hidden
    __syncthreads();

    if (tid < G) {
        const float4* wbr = (const float4*)(w_ih_b + (size_t)tid * NI);
        const float4* xv = (const float4*)xb_s;
        float a0 = 0.f, a1 = 0.f, a2 = 0.f, a3 = 0.f;
#pragma unroll
        for (int i = 0; i < 20; ++i) {
            float4 wv = wbr[i]; float4 x4 = xv[i];
            a0 = fmaf(wv.x, x4.x, a0); a1 = fmaf(wv.y, x4.y, a1);
            a2 = fmaf(wv.z, x4.z, a2); a3 = fmaf(wv.w, x4.w, a3);
        }
        tail_gx[tid] = b_ih_b[tid] + ((a0 + a1) + (a2 + a3));
    }
    __syncthreads();

    if (tid < H) {
        float r = sigf(tail_gx[tid] + b_hh_b[tid]);
        float z = sigf(tail_gx[tid + H] + b_hh_b[tid + H]);
        float n = tanhfast(tail_gx[tid + 2 * H] + r * b_hh_b[tid + 2 * H]);
        last_s[H + tid] = (1.f - z) * n;  // + z*0
    }
    __syncthreads();

    if (tid < 64) {
        const float4* w1r = (const float4*)(w1 + (size_t)tid * 2 * H);
        const float4* lv = (const float4*)last_s;
        float a0 = 0.f, a1 = 0.f, a2 = 0.f, a3 = 0.f;
#pragma unroll
        for (int i = 0; i < 64; ++i) {
            float4 wv = w1r[i]; float4 l4 = lv[i];
            a0 = fmaf(wv.x, l4.x, a0); a1 = fmaf(wv.y, l4.y, a1);
            a2 = fmaf(wv.z, l4.z, a2); a3 = fmaf(wv.w, l4.w, a3);
        }
        float v = b1[tid] + ((a0 + a1) + (a2 + a3));
        v = fmaxf(v, 0.f) * w2[tid];
#pragma unroll
        for (int off = 32; off > 0; off >>= 1) v += __shfl_down(v, off);
        if (tid == 0) out[b] = v + b2[0];
    }
}

extern "C" void kernel_launch(void* const* d_in, const int* in_sizes, int n_in,
                              void* d_out, int out_size, void* d_ws, size_t ws_size,
                              hipStream_t stream) {
    (void)in_sizes; (void)n_in; (void)out_size;
    const float* x      = (const float*)d_in[0];
    const float* w_ih_f = (const float*)d_in[1];
    const float* w_hh_f = (const float*)d_in[2];
    const float* b_ih_f = (const float*)d_in[3];
    const float* b_hh_f = (const float*)d_in[4];
    const float* w_ih_b = (const float*)d_in[5];
    const float* w_hh_b = (const float*)d_in[6];  // unused: h0=0 makes gh_b = b_hh_b
    const float* b_ih_b = (const float*)d_in[7];
    const float* b_hh_b = (const float*)d_in[8];
    const float* w1     = (const float*)d_in[9];
    const float* b1     = (const float*)d_in[10];
    const float* w2     = (const float*)d_in[11];
    const float* b2     = (const float*)d_in[12];
    (void)w_hh_b;
    float* out = (float*)d_out;

    float* h_state = (float*)d_ws;                 // B*H floats
    float* gxbuf = h_state + B * H;
    size_t hbytes = (size_t)B * H * sizeof(float);
    size_t avail = ws_size > hbytes ? ws_size - hbytes : 0;
    long long chunkT = (long long)(avail / ((size_t)B * G * sizeof(float)));
    if (chunkT > T) chunkT = T;
    if (chunkT < 1) chunkT = 1;

    for (int t0 = 0; t0 < T; t0 += (int)chunkT) {
        int ct = (T - t0 < (int)chunkT) ? (T - t0) : (int)chunkT;
        int ntiles = (ct + 511) / 512;
        gx_gemm_kernel<<<dim3(B * ntiles), dim3(256), 0, stream>>>(
            x, w_ih_f, b_ih_f, gxbuf, t0, ct);
        scan_kernel<<<dim3(B), dim3(512), 0, stream>>>(
            gxbuf, w_hh_f, b_hh_f, h_state, ct,
            (t0 == 0) ? 1 : 0, (t0 + ct >= T) ? 1 : 0,
            x, w_ih_b, b_ih_b, b_hh_b, w1, b1, w2, b2, out);
    }
}

// Round 4
// 1163.258 us; speedup vs baseline: 1.9689x; 1.9689x over previous
//
#include <hip/hip_runtime.h>

#define B 128
#define T 1500
#define NI 80        // N_MELS
#define H 128        // HIDDEN
#define G 384        // 3*H
#define TT 64        // t-tile for gx gemm

typedef float v2f __attribute__((ext_vector_type(2)));

__device__ __forceinline__ float sigf(float x) { return 1.0f / (1.0f + __expf(-x)); }
__device__ __forceinline__ float tanhfast(float x) { return 1.0f - 2.0f / (1.0f + __expf(2.0f * x)); }
__device__ __forceinline__ v2f pkfma(v2f a, v2f b, v2f c) { return __builtin_elementwise_fma(a, b, c); }

// ---------------- gx GEMM ----------------
// Block = (t-tile of 64, batch b). 384 threads, thread = output g, w row in VGPRs (packed),
// x tile staged in LDS (coalesced float4), broadcast-read per timestep. 2 timesteps/iter.
__global__ __launch_bounds__(384)
void gx_gemm_kernel(const float* __restrict__ x, const float* __restrict__ w_ih,
                    const float* __restrict__ b_ih, float* __restrict__ gx,
                    int t0, int ct) {
    int tile = blockIdx.x;
    int b = blockIdx.y;
    int tl0 = tile * TT;
    if (tl0 >= ct) return;
    int n = (ct - tl0 < TT) ? (ct - tl0) : TT;
    int tid = threadIdx.x;  // = output g

    __shared__ __align__(16) float xs[TT * NI];   // 20 KB
    const float4* xsrc4 = (const float4*)(x + ((size_t)b * T + (size_t)(t0 + tl0)) * NI);
    int total4 = n * (NI / 4);
    for (int i = tid; i < total4; i += 384) ((float4*)xs)[i] = xsrc4[i];

    v2f w2[40];
    const v2f* wr = (const v2f*)(w_ih + (size_t)tid * NI);
#pragma unroll
    for (int i = 0; i < 40; ++i) w2[i] = wr[i];
    float bias = b_ih[tid];
    __syncthreads();

    float* gout = gx + ((size_t)b * ct + (size_t)tl0) * G + tid;
    int tt = 0;
    for (; tt + 2 <= n; tt += 2) {
        const float4* xa4 = (const float4*)(xs + tt * NI);
        const float4* xb4 = (const float4*)(xs + (tt + 1) * NI);
        v2f a0 = {0.f, 0.f}, a1 = {0.f, 0.f}, c0 = {0.f, 0.f}, c1 = {0.f, 0.f};
#pragma unroll
        for (int i = 0; i < 20; ++i) {
            float4 xa = xa4[i];
            float4 xb = xb4[i];
            v2f alo = {xa.x, xa.y}, ahi = {xa.z, xa.w};
            v2f blo = {xb.x, xb.y}, bhi = {xb.z, xb.w};
            a0 = pkfma(w2[2 * i], alo, a0);
            a1 = pkfma(w2[2 * i + 1], ahi, a1);
            c0 = pkfma(w2[2 * i], blo, c0);
            c1 = pkfma(w2[2 * i + 1], bhi, c1);
        }
        gout[(size_t)tt * G]       = bias + ((a0.x + a0.y) + (a1.x + a1.y));
        gout[(size_t)(tt + 1) * G] = bias + ((c0.x + c0.y) + (c1.x + c1.y));
    }
    if (tt < n) {
        const float4* xa4 = (const float4*)(xs + tt * NI);
        v2f a0 = {0.f, 0.f}, a1 = {0.f, 0.f};
#pragma unroll
        for (int i = 0; i < 20; ++i) {
            float4 xa = xa4[i];
            v2f alo = {xa.x, xa.y}, ahi = {xa.z, xa.w};
            a0 = pkfma(w2[2 * i], alo, a0);
            a1 = pkfma(w2[2 * i + 1], ahi, a1);
        }
        gout[(size_t)tt * G] = bias + ((a0.x + a0.y) + (a1.x + a1.y));
    }
}

// ---------------- scan ----------------
// 512 threads: tid = j*4 + q, j in [0,128), q in [0,4). Thread holds W_hh rows
// {j, j+H, j+2H}, k-slice [32q, 32q+32) as packed float2 (48 pk_fma/step).
// Reduce: xor1 + xor2 (pure DPP quad reduce). All lanes compute gates (no branch);
// only q==0 writes h. h double-buffered in LDS with 36-float q-slice stride
// (4-word pad -> conflict-free). Raw s_barrier + lgkmcnt-only wait keeps the gx
// prefetch loads (distance 2) in flight across barriers.
__global__ __launch_bounds__(512)
void scan_kernel(const float* __restrict__ gx, const float* __restrict__ w_hh,
                 const float* __restrict__ b_hh, float* __restrict__ h_state,
                 int ct, int first, int last,
                 const float* __restrict__ x,
                 const float* __restrict__ w_ih_b, const float* __restrict__ b_ih_b,
                 const float* __restrict__ b_hh_b,
                 const float* __restrict__ w1, const float* __restrict__ b1,
                 const float* __restrict__ w2, const float* __restrict__ b2,
                 float* __restrict__ out) {
    int b = blockIdx.x;
    int tid = threadIdx.x;
    int j = tid >> 2;
    int q = tid & 3;
    int jpad = j + ((j >> 5) << 2);   // write index matching 36-float slice stride

    __shared__ __align__(16) float hs0[144];
    __shared__ __align__(16) float hs1[144];
    __shared__ __align__(16) float tail_gx[G];
    __shared__ __align__(16) float last_s[2 * H];
    __shared__ __align__(16) float xb_s[NI];

    // W_hh fragments as packed pairs
    v2f WR[16], WZ[16], WN[16];
    {
        const v2f* p0 = (const v2f*)(w_hh + (size_t)j * H + 32 * q);
        const v2f* p1 = (const v2f*)(w_hh + (size_t)(j + H) * H + 32 * q);
        const v2f* p2 = (const v2f*)(w_hh + (size_t)(j + 2 * H) * H + 32 * q);
#pragma unroll
        for (int i = 0; i < 16; ++i) { WR[i] = p0[i]; WZ[i] = p1[i]; WN[i] = p2[i]; }
    }
    float br = b_hh[j], bz = b_hh[j + H], bn = b_hh[j + 2 * H];

    float h_cur = 0.f;
    if (!first) h_cur = h_state[b * H + j];
    if (q == 0) hs0[jpad] = h_cur;

    // gx prefetch registers, distance 2 (set A for even t, set B for odd t)
    float ga0, ga1, ga2, gb0 = 0.f, gb1 = 0.f, gb2 = 0.f;
    {
        const float* gp = gx + (size_t)b * ct * G;
        ga0 = gp[j]; ga1 = gp[j + H]; ga2 = gp[j + 2 * H];
        if (ct > 1) { gb0 = gp[G + j]; gb1 = gp[G + j + H]; gb2 = gp[G + j + 2 * H]; }
    }
    asm volatile("s_waitcnt lgkmcnt(0)\n\ts_barrier" ::: "memory");

    auto step = [&](int TL, const float* SRC, float* DST, float& g0, float& g1, float& g2) {
        const float4* hv4 = (const float4*)(SRC + 36 * q);
        v2f arv = {0.f, 0.f}, azv = {0.f, 0.f}, anv = {0.f, 0.f};
#pragma unroll
        for (int i = 0; i < 8; ++i) {
            float4 hv = hv4[i];
            v2f hlo = {hv.x, hv.y}, hhi = {hv.z, hv.w};
            arv = pkfma(WR[2 * i], hlo, arv);
            azv = pkfma(WZ[2 * i], hlo, azv);
            anv = pkfma(WN[2 * i], hlo, anv);
            arv = pkfma(WR[2 * i + 1], hhi, arv);
            azv = pkfma(WZ[2 * i + 1], hhi, azv);
            anv = pkfma(WN[2 * i + 1], hhi, anv);
        }
        float ar = arv.x + arv.y, az = azv.x + azv.y, an = anv.x + anv.y;
        ar += __shfl_xor(ar, 1); az += __shfl_xor(az, 1); an += __shfl_xor(an, 1);
        ar += __shfl_xor(ar, 2); az += __shfl_xor(az, 2); an += __shfl_xor(an, 2);
        float r = sigf(g0 + br + ar);
        float z = sigf(g1 + bz + az);
        float n = tanhfast(g2 + r * (bn + an));
        h_cur = (1.f - z) * n + z * h_cur;
        if (q == 0) DST[jpad] = h_cur;
        if (TL + 2 < ct) {
            const float* gp = gx + ((size_t)b * ct + TL + 2) * G;
            g0 = gp[j]; g1 = gp[j + H]; g2 = gp[j + 2 * H];
        }
        asm volatile("s_waitcnt lgkmcnt(0)\n\ts_barrier" ::: "memory");
    };

    int tl = 0;
    for (; tl + 1 < ct; tl += 2) {
        step(tl,     hs0, hs1, ga0, ga1, ga2);
        step(tl + 1, hs1, hs0, gb0, gb1, gb2);
    }
    if (tl < ct) step(tl, hs0, hs1, ga0, ga1, ga2);

    if (!last) {
        if (q == 0) h_state[b * H + j] = h_cur;
        return;
    }

    // ---- backward single step (h0 = 0) + MLP head ----
    if (tid < NI) xb_s[tid] = x[((size_t)b * T + (T - 1)) * NI + tid];
    if (q == 0) last_s[j] = h_cur;  // forward final hidden
    __syncthreads();

    if (tid < G) {
        const float4* wbr = (const float4*)(w_ih_b + (size_t)tid * NI);
        const float4* xv = (const float4*)xb_s;
        float a0 = 0.f, a1 = 0.f, a2 = 0.f, a3 = 0.f;
#pragma unroll
        for (int i = 0; i < 20; ++i) {
            float4 wv = wbr[i]; float4 x4 = xv[i];
            a0 = fmaf(wv.x, x4.x, a0); a1 = fmaf(wv.y, x4.y, a1);
            a2 = fmaf(wv.z, x4.z, a2); a3 = fmaf(wv.w, x4.w, a3);
        }
        tail_gx[tid] = b_ih_b[tid] + ((a0 + a1) + (a2 + a3));
    }
    __syncthreads();

    if (tid < H) {
        float r = sigf(tail_gx[tid] + b_hh_b[tid]);
        float z = sigf(tail_gx[tid + H] + b_hh_b[tid + H]);
        float n = tanhfast(tail_gx[tid + 2 * H] + r * b_hh_b[tid + 2 * H]);
        last_s[H + tid] = (1.f - z) * n;  // + z*0
    }
    __syncthreads();

    if (tid < 64) {
        const float4* w1r = (const float4*)(w1 + (size_t)tid * 2 * H);
        const float4* lv = (const float4*)last_s;
        float a0 = 0.f, a1 = 0.f, a2 = 0.f, a3 = 0.f;
#pragma unroll
        for (int i = 0; i < 64; ++i) {
            float4 wv = w1r[i]; float4 l4 = lv[i];
            a0 = fmaf(wv.x, l4.x, a0); a1 = fmaf(wv.y, l4.y, a1);
            a2 = fmaf(wv.z, l4.z, a2); a3 = fmaf(wv.w, l4.w, a3);
        }
        float v = b1[tid] + ((a0 + a1) + (a2 + a3));
        v = fmaxf(v, 0.f) * w2[tid];
#pragma unroll
        for (int off = 32; off > 0; off >>= 1) v += __shfl_down(v, off);
        if (tid == 0) out[b] = v + b2[0];
    }
}

extern "C" void kernel_launch(void* const* d_in, const int* in_sizes, int n_in,
                              void* d_out, int out_size, void* d_ws, size_t ws_size,
                              hipStream_t stream) {
    (void)in_sizes; (void)n_in; (void)out_size;
    const float* x      = (const float*)d_in[0];
    const float* w_ih_f = (const float*)d_in[1];
    const float* w_hh_f = (const float*)d_in[2];
    const float* b_ih_f = (const float*)d_in[3];
    const float* b_hh_f = (const float*)d_in[4];
    const float* w_ih_b = (const float*)d_in[5];
    const float* w_hh_b = (const float*)d_in[6];  // unused: h0=0 makes gh_b = b_hh_b
    const float* b_ih_b = (const float*)d_in[7];
    const float* b_hh_b = (const float*)d_in[8];
    const float* w1     = (const float*)d_in[9];
    const float* b1     = (const float*)d_in[10];
    const float* w2     = (const float*)d_in[11];
    const float* b2     = (const float*)d_in[12];
    (void)w_hh_b;
    float* out = (float*)d_out;

    float* h_state = (float*)d_ws;                 // B*H floats
    float* gxbuf = h_state + B * H;
    size_t hbytes = (size_t)B * H * sizeof(float);
    size_t avail = ws_size > hbytes ? ws_size - hbytes : 0;
    long long chunkT = (long long)(avail / ((size_t)B * G * sizeof(float)));
    if (chunkT > T) chunkT = T;
    if (chunkT < 1) chunkT = 1;

    for (int t0 = 0; t0 < T; t0 += (int)chunkT) {
        int ct = (T - t0 < (int)chunkT) ? (T - t0) : (int)chunkT;
        int ntiles = (ct + TT - 1) / TT;
        gx_gemm_kernel<<<dim3(ntiles, B), dim3(384), 0, stream>>>(
            x, w_ih_f, b_ih_f, gxbuf, t0, ct);
        scan_kernel<<<dim3(B), dim3(512), 0, stream>>>(
            gxbuf, w_hh_f, b_hh_f, h_state, ct,
            (t0 == 0) ? 1 : 0, (t0 + ct >= T) ? 1 : 0,
            x, w_ih_b, b_ih_b, b_hh_b, w1, b1, w2, b2, out);
    }
}